// Round 16
// baseline (501.423 us; speedup 1.0000x reference)
//
#include <hip/hip_runtime.h>
#include <hip/hip_bf16.h>

#define BDIM 32
#define TDIM 1024
#define HDIM 1024
#define AS1 __attribute__((address_space(1)))
#define AS3 __attribute__((address_space(3)))

typedef __attribute__((ext_vector_type(8))) short short8;
typedef __attribute__((ext_vector_type(8))) unsigned short ushort8;
typedef __attribute__((ext_vector_type(4))) unsigned short u16x4;
typedef __attribute__((ext_vector_type(4))) float f32x4;

__device__ __forceinline__ float b2f(unsigned short h){ return __uint_as_float(((unsigned)h)<<16); }
__device__ __forceinline__ unsigned short f2b(float f){
  unsigned u = __float_as_uint(f);
  u += 0x7fffu + ((u>>16)&1u);
  return (unsigned short)(u>>16);
}
__device__ __forceinline__ float gelu_f(float v){ return 0.5f*v*(1.0f+erff(v*0.70710678118f)); }
__device__ __forceinline__ void stv(float* p, float v){ *p = v; }
__device__ __forceinline__ void stv(unsigned short* p, float v){ *p = f2b(v); }
__device__ __forceinline__ float ldr(float v){ return v; }
__device__ __forceinline__ float ldr(unsigned short v){ return b2f(v); }

// ---- convert weights fp32->bf16; tril-mask (incl. diagonal) the temporal ones ----
__global__ void prep_weights(const float* __restrict__ w1, const float* __restrict__ w2,
                             const float* __restrict__ c1, const float* __restrict__ c2,
                             unsigned short* __restrict__ w1m, unsigned short* __restrict__ w2m,
                             unsigned short* __restrict__ c1b, unsigned short* __restrict__ c2b){
  int idx = blockIdx.x*blockDim.x + threadIdx.x;
  int e = idx*4;
  int i = e >> 10, j0 = e & 1023;
  f32x4 a = *(const f32x4*)(w1+e);
  f32x4 b = *(const f32x4*)(w2+e);
  f32x4 c = *(const f32x4*)(c1+e);
  f32x4 d = *(const f32x4*)(c2+e);
  u16x4 av, bv, cv, dv;
  #pragma unroll
  for (int q=0;q<4;++q){
    float am = (j0+q <= i) ? a[q] : 0.f;
    float bm = (j0+q <= i) ? b[q] : 0.f;
    av[q]=f2b(am); bv[q]=f2b(bm); cv[q]=f2b(c[q]); dv[q]=f2b(d[q]);
  }
  *(u16x4*)(w1m+e)=av; *(u16x4*)(w2m+e)=bv; *(u16x4*)(c1b+e)=cv; *(u16x4*)(c2b+e)=dv;
}

// ---------------- LayerNorm row stats: one wave per 1024-wide fp32 row ----------------
__global__ void ln_stats(const float* __restrict__ p, float* __restrict__ mean,
                         float* __restrict__ rstd){
  int wid = threadIdx.x>>6, lane = threadIdx.x&63;
  int row = blockIdx.x*4 + wid;
  const float* pr = p + (size_t)row*HDIM;
  float s=0.f, s2=0.f;
  #pragma unroll
  for (int it=0; it<4; ++it){
    f32x4 v = *(const f32x4*)(pr + it*256 + lane*4);
    #pragma unroll
    for (int c=0;c<4;++c){ s += v[c]; s2 += v[c]*v[c]; }
  }
  #pragma unroll
  for (int off=32; off>0; off>>=1){ s += __shfl_xor(s,off,64); s2 += __shfl_xor(s2,off,64); }
  if (lane==0){
    float m = s * (1.0f/HDIM);
    float var = s2 * (1.0f/HDIM) - m*m;
    mean[row]=m; rstd[row]=rsqrtf(var + 1e-5f);
  }
}

// ---- normalize + transpose: x[b,t,h] fp32 -> xnT[b,h,t] bf16 (64x64 LDS tiles) ----
__global__ void ln_norm_transpose(const float* __restrict__ x, const float* __restrict__ mean,
                                  const float* __restrict__ rstd, const float* __restrict__ g,
                                  const float* __restrict__ bta, unsigned short* __restrict__ xnT){
  __shared__ float tile[64][65];
  int t0 = blockIdx.x*64, h0 = blockIdx.y*64, b = blockIdx.z;
  int tid = threadIdx.x;
  int rr = tid>>3, c8 = tid&7;
  size_t base = (size_t)b*TDIM*HDIM;
  #pragma unroll
  for (int p=0;p<2;++p){
    int r = rr + p*32;
    int trow = t0 + r;
    float m = mean[b*TDIM + trow], rs = rstd[b*TDIM + trow];
    f32x4 v0 = *(const f32x4*)(x + base + (size_t)trow*HDIM + h0 + c8*8);
    f32x4 v1 = *(const f32x4*)(x + base + (size_t)trow*HDIM + h0 + c8*8 + 4);
    #pragma unroll
    for (int c=0;c<4;++c){
      int h = c8*8+c;
      tile[r][h]   = (v0[c]-m)*rs*g[h0+h]   + bta[h0+h];
      tile[r][h+4] = (v1[c]-m)*rs*g[h0+h+4] + bta[h0+h+4];
    }
  }
  __syncthreads();
  #pragma unroll
  for (int p=0;p<2;++p){
    int hr = rr + p*32;
    ushort8 ov;
    #pragma unroll
    for (int c=0;c<8;++c) ov[c] = f2b(tile[c8*8+c][hr]);
    *(ushort8*)(xnT + base + (size_t)(h0+hr)*TDIM + t0 + c8*8) = ov;
  }
}

// ---- LN2 fused single-pass: bf16 in, bf16 out ----
__global__ void ln_fused(const unsigned short* __restrict__ p, const float* __restrict__ g,
                         const float* __restrict__ bta, unsigned short* __restrict__ o){
  int wid = threadIdx.x>>6, lane = threadIdx.x&63;
  size_t row = (size_t)blockIdx.x*4 + wid;
  const unsigned short* pr = p + row*HDIM + lane*16;
  ushort8 v0 = *(const ushort8*)(pr);
  ushort8 v1 = *(const ushort8*)(pr+8);
  float f[16];
  float s=0.f, s2=0.f;
  #pragma unroll
  for (int c=0;c<8;++c){ f[c]=b2f(v0[c]); f[c+8]=b2f(v1[c]); }
  #pragma unroll
  for (int c=0;c<16;++c){ s += f[c]; s2 += f[c]*f[c]; }
  #pragma unroll
  for (int off=32; off>0; off>>=1){ s += __shfl_xor(s,off,64); s2 += __shfl_xor(s2,off,64); }
  float m = s * (1.0f/HDIM);
  float rs = rsqrtf(s2*(1.0f/HDIM) - m*m + 1e-5f);
  int h0 = lane*16;
  ushort8 o0, o1;
  #pragma unroll
  for (int c=0;c<8;++c){
    o0[c] = f2b((f[c]-m)*rs*g[h0+c] + bta[h0+c]);
    o1[c] = f2b((f[c+8]-m)*rs*g[h0+c+8] + bta[h0+c+8]);
  }
  *(ushort8*)(o + row*HDIM + h0) = o0;
  *(ushort8*)(o + row*HDIM + h0 + 8) = o1;
}

// ======== 256x256 BK=64, 8-wave, quadrant-phase GEMM — deep-prefetch, static-offset ========
// Per K-tile: stage ALL 4 halves of t+1 at P0 (after end-P3(t-1) BAR retired t-1 readers),
// ONE GATE(8) (exactly retires tile-t's 8 loads), ds_reads of P0 moved AFTER the gate.
// 2 K-tiles per loop iteration -> LDS buffer offsets are compile-time constants.
#define GATE(N) asm volatile("s_waitcnt vmcnt(" #N ")" ::: "memory")
#define BAR()   __builtin_amdgcn_s_barrier()

template<int MODE, typename CT, typename RT>
__global__ __launch_bounds__(512,1)
void gemmq(const unsigned short* __restrict__ act, const unsigned short* __restrict__ wgt,
           CT* __restrict__ C, const float* __restrict__ bias, const RT* __restrict__ resid){
  extern __shared__ char LDS[];
  const int bid = blockIdx.x;
  const int tile = (bid & 7)*64 + (bid >> 3);
  const int panel = tile >> 2;
  int inner = tile & 3;
  if constexpr (MODE==1 || MODE==2){ if (bid & 256) inner ^= 3; }  // tril load-balance
  const unsigned short *pa, *pb;
  size_t cbase; int rg0, cg0, kend;
  if constexpr (MODE==1){
    int b = panel>>2, mt = panel&3;
    pa = act + (size_t)b*1048576 + (size_t)mt*262144;
    pb = wgt + (size_t)inner*262144;
    kend = (inner+1)*256;
    cbase = (size_t)b*1048576; rg0 = mt*256; cg0 = inner*256;
  } else if constexpr (MODE==2){
    int b = panel>>2, nt = panel&3;
    pa = wgt + (size_t)inner*262144;
    pb = act + (size_t)b*1048576 + (size_t)nt*262144;
    kend = (inner+1)*256;
    cbase = (size_t)b*1048576; rg0 = inner*256; cg0 = nt*256;
  } else {
    pa = act + (size_t)panel*262144;
    pb = wgt + (size_t)inner*262144;
    kend = 1024;
    cbase = 0; rg0 = panel*256; cg0 = inner*256;
  }
  const int tid = threadIdx.x, lane = tid&63, wid = tid>>6;
  const int wrow = (wid>>2)*64;       // A-row base within quadrant
  const int wcol = (wid&3)*32;        // B-row (C-col) base within quadrant
  const int l15 = lane&15, l4b = (lane>>4)<<4;
  f32x4 acc[8][4];
  #pragma unroll
  for (int i=0;i<8;++i)
    #pragma unroll
    for (int j=0;j<4;++j) acc[i][j] = (f32x4)(0.f);

  const int NT = kend>>6;   // always even (4/8/12/16)

  // half ids: 0=A rows0-127, 1=A rows128-255, 2=B rows0-127, 3=B rows128-255
  auto STAGE = [&](int dstbuf, int half, int st){
    const unsigned short* src = (half<2) ? pa : pb;
    const int rbase = (half&1)<<7;
    char* dst = LDS + (dstbuf<<16) + (half<<14);
    const int k0 = st<<6;
    #pragma unroll
    for (int l=0;l<2;++l){
      int W = tid*16 + (l<<13);
      int r = W>>7;
      int cs = (W&127) ^ ((r&7)<<4);            // inverse swizzle on global source
      __builtin_amdgcn_global_load_lds(
        (const AS1 void*)(src + (size_t)(rbase+r)*1024 + k0 + (cs>>1)),
        (AS3 void*)(dst + W), 16, 0, 0);
    }
  };

  auto LDA = [&](int buf, int qa, int i, int s)->short8{
    int ra = wrow + i*16 + l15;
    int L = (ra<<7) + (((s<<6) + l4b) ^ ((ra&7)<<4));
    return *(const short8*)(LDS + (buf<<16) + (qa<<14) + L);
  };
  auto LDB = [&](int buf, int qb, int j, int s)->short8{
    int rb = wcol + j*16 + l15;
    int L = (rb<<7) + (((s<<6) + l4b) ^ ((rb&7)<<4));
    return *(const short8*)(LDS + (buf<<16) + ((2+qb)<<14) + L);
  };

  short8 aR[2][4], bR[2][2];

#define MFMAQ(qa,qb)                                                         \
  __builtin_amdgcn_s_setprio(1);                                             \
  _Pragma("unroll") for (int s=0;s<2;++s)                                    \
    _Pragma("unroll") for (int i=0;i<4;++i)                                  \
      _Pragma("unroll") for (int j=0;j<2;++j)                                \
        acc[(qa)*4+i][(qb)*2+j] = __builtin_amdgcn_mfma_f32_16x16x32_bf16(   \
            aR[s][i], bR[s][j], acc[(qa)*4+i][(qb)*2+j], 0,0,0);             \
  __builtin_amdgcn_s_setprio(0);

// one K-tile: BUF literal; TT runtime tile index. Stage all4(TT+1) -> buf BUF^1,
// clamped source for tail dummies. 1 gate + 2 barriers.
#define TILE_BODY(BUF, TT)                                                   \
  {                                                                          \
    const int nsrc = ((TT)+1 < NT) ? (TT)+1 : (TT);                          \
    STAGE(BUF^1, 0, nsrc); STAGE(BUF^1, 2, nsrc);                            \
    STAGE(BUF^1, 1, nsrc); STAGE(BUF^1, 3, nsrc);                            \
    GATE(8); BAR();                                                          \
    _Pragma("unroll") for (int s=0;s<2;++s){                                 \
      _Pragma("unroll") for (int i=0;i<4;++i) aR[s][i] = LDA(BUF,0,i,s);     \
      _Pragma("unroll") for (int j=0;j<2;++j) bR[s][j] = LDB(BUF,0,j,s);     \
    }                                                                        \
    MFMAQ(0,0)                                                               \
    _Pragma("unroll") for (int s=0;s<2;++s)                                  \
      _Pragma("unroll") for (int j=0;j<2;++j) bR[s][j] = LDB(BUF,1,j,s);     \
    MFMAQ(0,1)                                                               \
    _Pragma("unroll") for (int s=0;s<2;++s)                                  \
      _Pragma("unroll") for (int i=0;i<4;++i) aR[s][i] = LDA(BUF,1,i,s);     \
    MFMAQ(1,1)                                                               \
    _Pragma("unroll") for (int s=0;s<2;++s)                                  \
      _Pragma("unroll") for (int j=0;j<2;++j) bR[s][j] = LDB(BUF,0,j,s);     \
    MFMAQ(1,0)                                                               \
    BAR();                                                                   \
  }

  // prologue: tile 0 fully staged + drained
  STAGE(0,0,0); STAGE(0,2,0); STAGE(0,1,0); STAGE(0,3,0);
  GATE(0); BAR();

  for (int t=0; t<NT; t+=2){
    TILE_BODY(0, t)
    TILE_BODY(1, t+1)
  }
#undef TILE_BODY
#undef MFMAQ

  GATE(0);   // drain tail dummy DMAs before block retire / LDS reuse

  // epilogue: acc[I][J], I=qa*4+i, J=qb*2+j; frag row=(lane>>4)*4+r, col=lane&15
  #pragma unroll
  for (int I=0;I<8;++I){
    int rbase = rg0 + (I>>2)*128 + wrow + (I&3)*16 + ((lane>>4)<<2);
    #pragma unroll
    for (int J=0;J<4;++J){
      int cg = cg0 + (J>>1)*128 + wcol + (J&1)*16 + l15;
      float bn = (MODE!=2) ? bias[cg] : 0.f;
      #pragma unroll
      for (int r=0;r<4;++r){
        int rg = rbase + r;
        float v = acc[I][J][r];
        if (MODE==1 || MODE==3){ v += bn; v = gelu_f(v); }
        else if (MODE==2){ v += bias[rg]; v += ldr(resid[cbase + (size_t)rg*1024 + cg]); }
        else { v += bn; v += ldr(resid[cbase + (size_t)rg*1024 + cg]); }
        stv(&C[cbase + (size_t)rg*1024 + cg], v);
      }
    }
  }
}

extern "C" void kernel_launch(void* const* d_in, const int* in_sizes, int n_in,
                              void* d_out, int out_size, void* d_ws, size_t ws_size,
                              hipStream_t stream){
  const float* x    = (const float*)d_in[0];
  const float* tw1  = (const float*)d_in[1];
  const float* tb1  = (const float*)d_in[2];
  const float* tw2  = (const float*)d_in[3];
  const float* tb2  = (const float*)d_in[4];
  const float* cw1  = (const float*)d_in[5];
  const float* cb1  = (const float*)d_in[6];
  const float* cw2  = (const float*)d_in[7];
  const float* cb2  = (const float*)d_in[8];
  const float* g1   = (const float*)d_in[9];
  const float* bb1  = (const float*)d_in[10];
  const float* g2   = (const float*)d_in[11];
  const float* bb2  = (const float*)d_in[12];
  float* out = (float*)d_out;

  char* ws = (char*)d_ws;
  unsigned short* bufA = (unsigned short*)(ws);                    // 64MB bf16
  unsigned short* bufB = (unsigned short*)(ws + 67108864);         // 64MB bf16
  unsigned short* xmid = (unsigned short*)(ws + 134217728);        // 64MB bf16 x_mid
  unsigned short* w1m  = (unsigned short*)(ws + 201326592);        // 2MB
  unsigned short* w2m  = (unsigned short*)(ws + 203423744);        // 2MB
  unsigned short* c1b  = (unsigned short*)(ws + 205520896);        // 2MB
  unsigned short* c2b  = (unsigned short*)(ws + 207618048);        // 2MB
  float* meanb = (float*)(ws + 209715200);                         // 128KB
  float* rstdb = (float*)(ws + 209846272);                         // 128KB

  prep_weights<<<1024,256,0,stream>>>(tw1,tw2,cw1,cw2,w1m,w2m,c1b,c2b);
  // temporal path
  ln_stats<<<8192,256,0,stream>>>(x, meanb, rstdb);
  ln_norm_transpose<<<dim3(16,16,32),256,0,stream>>>(x, meanb, rstdb, g1, bb1, bufA);
  gemmq<1,unsigned short,float><<<512,512,131072,stream>>>(bufA, w1m, bufB, tb1, (const float*)nullptr);
  gemmq<2,unsigned short,float><<<512,512,131072,stream>>>(bufB, w2m, xmid, tb2, x);
  // channel path
  ln_fused<<<8192,256,0,stream>>>(xmid, g2, bb2, bufA);
  gemmq<3,unsigned short,unsigned short><<<512,512,131072,stream>>>(bufA, c1b, bufB, cb1, (const unsigned short*)nullptr);
  gemmq<4,float,unsigned short><<<512,512,131072,stream>>>(bufB, c2b, out, cb2, xmid);
}

// Round 17
// 483.580 us; speedup vs baseline: 1.0369x; 1.0369x over previous
//
#include <hip/hip_runtime.h>
#include <hip/hip_bf16.h>

#define BDIM 32
#define TDIM 1024
#define HDIM 1024
#define AS1 __attribute__((address_space(1)))
#define AS3 __attribute__((address_space(3)))

typedef __attribute__((ext_vector_type(8))) short short8;
typedef __attribute__((ext_vector_type(8))) unsigned short ushort8;
typedef __attribute__((ext_vector_type(4))) unsigned short u16x4;
typedef __attribute__((ext_vector_type(4))) float f32x4;

__device__ __forceinline__ float b2f(unsigned short h){ return __uint_as_float(((unsigned)h)<<16); }
__device__ __forceinline__ unsigned short f2b(float f){
  unsigned u = __float_as_uint(f);
  u += 0x7fffu + ((u>>16)&1u);
  return (unsigned short)(u>>16);
}
__device__ __forceinline__ float gelu_f(float v){ return 0.5f*v*(1.0f+erff(v*0.70710678118f)); }
__device__ __forceinline__ void stv(float* p, float v){ *p = v; }
__device__ __forceinline__ void stv(unsigned short* p, float v){ *p = f2b(v); }
__device__ __forceinline__ float ldr(float v){ return v; }
__device__ __forceinline__ float ldr(unsigned short v){ return b2f(v); }

// ---- convert weights fp32->bf16; tril-mask (incl. diagonal) the temporal ones ----
__global__ void prep_weights(const float* __restrict__ w1, const float* __restrict__ w2,
                             const float* __restrict__ c1, const float* __restrict__ c2,
                             unsigned short* __restrict__ w1m, unsigned short* __restrict__ w2m,
                             unsigned short* __restrict__ c1b, unsigned short* __restrict__ c2b){
  int idx = blockIdx.x*blockDim.x + threadIdx.x;
  int e = idx*4;
  int i = e >> 10, j0 = e & 1023;
  f32x4 a = *(const f32x4*)(w1+e);
  f32x4 b = *(const f32x4*)(w2+e);
  f32x4 c = *(const f32x4*)(c1+e);
  f32x4 d = *(const f32x4*)(c2+e);
  u16x4 av, bv, cv, dv;
  #pragma unroll
  for (int q=0;q<4;++q){
    float am = (j0+q <= i) ? a[q] : 0.f;
    float bm = (j0+q <= i) ? b[q] : 0.f;
    av[q]=f2b(am); bv[q]=f2b(bm); cv[q]=f2b(c[q]); dv[q]=f2b(d[q]);
  }
  *(u16x4*)(w1m+e)=av; *(u16x4*)(w2m+e)=bv; *(u16x4*)(c1b+e)=cv; *(u16x4*)(c2b+e)=dv;
}

// ---------------- LayerNorm row stats: one wave per 1024-wide fp32 row ----------------
__global__ void ln_stats(const float* __restrict__ p, float* __restrict__ mean,
                         float* __restrict__ rstd){
  int wid = threadIdx.x>>6, lane = threadIdx.x&63;
  int row = blockIdx.x*4 + wid;
  const float* pr = p + (size_t)row*HDIM;
  float s=0.f, s2=0.f;
  #pragma unroll
  for (int it=0; it<4; ++it){
    f32x4 v = *(const f32x4*)(pr + it*256 + lane*4);
    #pragma unroll
    for (int c=0;c<4;++c){ s += v[c]; s2 += v[c]*v[c]; }
  }
  #pragma unroll
  for (int off=32; off>0; off>>=1){ s += __shfl_xor(s,off,64); s2 += __shfl_xor(s2,off,64); }
  if (lane==0){
    float m = s * (1.0f/HDIM);
    float var = s2 * (1.0f/HDIM) - m*m;
    mean[row]=m; rstd[row]=rsqrtf(var + 1e-5f);
  }
}

// ---- normalize + transpose: x[b,t,h] fp32 -> xnT[b,h,t] bf16 (64x64 LDS tiles) ----
__global__ void ln_norm_transpose(const float* __restrict__ x, const float* __restrict__ mean,
                                  const float* __restrict__ rstd, const float* __restrict__ g,
                                  const float* __restrict__ bta, unsigned short* __restrict__ xnT){
  __shared__ float tile[64][65];
  int t0 = blockIdx.x*64, h0 = blockIdx.y*64, b = blockIdx.z;
  int tid = threadIdx.x;
  int rr = tid>>3, c8 = tid&7;
  size_t base = (size_t)b*TDIM*HDIM;
  #pragma unroll
  for (int p=0;p<2;++p){
    int r = rr + p*32;
    int trow = t0 + r;
    float m = mean[b*TDIM + trow], rs = rstd[b*TDIM + trow];
    f32x4 v0 = *(const f32x4*)(x + base + (size_t)trow*HDIM + h0 + c8*8);
    f32x4 v1 = *(const f32x4*)(x + base + (size_t)trow*HDIM + h0 + c8*8 + 4);
    #pragma unroll
    for (int c=0;c<4;++c){
      int h = c8*8+c;
      tile[r][h]   = (v0[c]-m)*rs*g[h0+h]   + bta[h0+h];
      tile[r][h+4] = (v1[c]-m)*rs*g[h0+h+4] + bta[h0+h+4];
    }
  }
  __syncthreads();
  #pragma unroll
  for (int p=0;p<2;++p){
    int hr = rr + p*32;
    ushort8 ov;
    #pragma unroll
    for (int c=0;c<8;++c) ov[c] = f2b(tile[c8*8+c][hr]);
    *(ushort8*)(xnT + base + (size_t)(h0+hr)*TDIM + t0 + c8*8) = ov;
  }
}

// ---- LN2 fused single-pass: bf16 in, bf16 out ----
__global__ void ln_fused(const unsigned short* __restrict__ p, const float* __restrict__ g,
                         const float* __restrict__ bta, unsigned short* __restrict__ o){
  int wid = threadIdx.x>>6, lane = threadIdx.x&63;
  size_t row = (size_t)blockIdx.x*4 + wid;
  const unsigned short* pr = p + row*HDIM + lane*16;
  ushort8 v0 = *(const ushort8*)(pr);
  ushort8 v1 = *(const ushort8*)(pr+8);
  float f[16];
  float s=0.f, s2=0.f;
  #pragma unroll
  for (int c=0;c<8;++c){ f[c]=b2f(v0[c]); f[c+8]=b2f(v1[c]); }
  #pragma unroll
  for (int c=0;c<16;++c){ s += f[c]; s2 += f[c]*f[c]; }
  #pragma unroll
  for (int off=32; off>0; off>>=1){ s += __shfl_xor(s,off,64); s2 += __shfl_xor(s2,off,64); }
  float m = s * (1.0f/HDIM);
  float rs = rsqrtf(s2*(1.0f/HDIM) - m*m + 1e-5f);
  int h0 = lane*16;
  ushort8 o0, o1;
  #pragma unroll
  for (int c=0;c<8;++c){
    o0[c] = f2b((f[c]-m)*rs*g[h0+c] + bta[h0+c]);
    o1[c] = f2b((f[c+8]-m)*rs*g[h0+c+8] + bta[h0+c+8]);
  }
  *(ushort8*)(o + row*HDIM + h0) = o0;
  *(ushort8*)(o + row*HDIM + h0 + 8) = o1;
}

// ======== 256x256 BK=64 GEMM — 16 waves (4 waves/SIMD) for TLP latency hiding ========
// Same tile/LDS/swizzle as r13 (verified, conflicts 0) but 1024 threads: per-wave output
// 64x64 (acc=64 VGPR), s-outer/j-inner operand reads keep live regs ~110 < 128 cap.
// Per K-tile: stage 4 halves of t+1 (1 gload/thread each), GATE(4)+BAR, reads+MFMA, BAR.
// 4 waves/SIMD cover ds_read->MFMA dependency stalls (m114 mechanism).
#define GATE(N) asm volatile("s_waitcnt vmcnt(" #N ")" ::: "memory")
#define BAR()   __builtin_amdgcn_s_barrier()

template<int MODE, typename CT, typename RT>
__global__ __launch_bounds__(1024,1)
void gemmw(const unsigned short* __restrict__ act, const unsigned short* __restrict__ wgt,
           CT* __restrict__ C, const float* __restrict__ bias, const RT* __restrict__ resid){
  extern __shared__ char LDS[];
  const int bid = blockIdx.x;
  const int tile = (bid & 7)*64 + (bid >> 3);
  const int panel = tile >> 2;
  int inner = tile & 3;
  if constexpr (MODE==1 || MODE==2){ if (bid & 256) inner ^= 3; }  // tril load-balance
  const unsigned short *pa, *pb;
  size_t cbase; int rg0, cg0, kend;
  if constexpr (MODE==1){
    int b = panel>>2, mt = panel&3;
    pa = act + (size_t)b*1048576 + (size_t)mt*262144;
    pb = wgt + (size_t)inner*262144;
    kend = (inner+1)*256;
    cbase = (size_t)b*1048576; rg0 = mt*256; cg0 = inner*256;
  } else if constexpr (MODE==2){
    int b = panel>>2, nt = panel&3;
    pa = wgt + (size_t)inner*262144;
    pb = act + (size_t)b*1048576 + (size_t)nt*262144;
    kend = (inner+1)*256;
    cbase = (size_t)b*1048576; rg0 = inner*256; cg0 = nt*256;
  } else {
    pa = act + (size_t)panel*262144;
    pb = wgt + (size_t)inner*262144;
    kend = 1024;
    cbase = 0; rg0 = panel*256; cg0 = inner*256;
  }
  const int tid = threadIdx.x, lane = tid&63, wid = tid>>6;   // 16 waves: 4x4
  const int wrow = (wid>>2)*64;       // A-row base within 256
  const int wcol = (wid&3)*64;        // C-col base within 256
  const int l15 = lane&15, l4b = (lane>>4)<<4;
  const int abase = (wrow>>7)<<14;    // A half offset
  const int bbase = 32768 + ((wcol>>7)<<14);   // B half offset
  const int arow0 = wrow & 127, brow0 = wcol & 127;
  f32x4 acc[4][4];
  #pragma unroll
  for (int i=0;i<4;++i)
    #pragma unroll
    for (int j=0;j<4;++j) acc[i][j] = (f32x4)(0.f);

  const int NT = kend>>6;   // always even

  // half ids: 0=A rows0-127, 1=A rows128-255, 2=B rows0-127, 3=B rows128-255
  auto STAGE = [&](int dstbuf, int half, int st){
    const unsigned short* src = (half<2) ? pa : pb;
    const int rbase = (half&1)<<7;
    char* dst = LDS + (dstbuf<<16) + (half<<14);
    int W = tid*16;                              // 1024 thr x 16B = one 16KB half
    int r = W>>7;
    int cs = (W&127) ^ ((r&7)<<4);               // inverse swizzle on global source
    __builtin_amdgcn_global_load_lds(
      (const AS1 void*)(src + (size_t)(rbase+r)*1024 + (st<<6) + (cs>>1)),
      (AS3 void*)(dst + W), 16, 0, 0);
  };

  auto LDA = [&](int buf, int i, int s)->short8{
    int ra = arow0 + i*16 + l15;
    int L = (ra<<7) + (((s<<6) + l4b) ^ ((ra&7)<<4));
    return *(const short8*)(LDS + (buf<<16) + abase + L);
  };
  auto LDB = [&](int buf, int j, int s)->short8{
    int rb = brow0 + j*16 + l15;
    int L = (rb<<7) + (((s<<6) + l4b) ^ ((rb&7)<<4));
    return *(const short8*)(LDS + (buf<<16) + bbase + L);
  };

// one K-tile: BUF literal, TT runtime. Stage t+1 (clamped) -> BUF^1; gate+bar; compute.
#define TILE_BODY(BUF, TT)                                                   \
  {                                                                          \
    const int nsrc = ((TT)+1 < NT) ? (TT)+1 : (TT);                          \
    STAGE(BUF^1, 0, nsrc); STAGE(BUF^1, 1, nsrc);                            \
    STAGE(BUF^1, 2, nsrc); STAGE(BUF^1, 3, nsrc);                            \
    GATE(4); BAR();                                                          \
    _Pragma("unroll") for (int s=0;s<2;++s){                                 \
      short8 aR[4];                                                          \
      _Pragma("unroll") for (int i=0;i<4;++i) aR[i] = LDA(BUF,i,s);          \
      _Pragma("unroll") for (int j=0;j<4;++j){                               \
        short8 bR = LDB(BUF,j,s);                                            \
        __builtin_amdgcn_s_setprio(1);                                       \
        _Pragma("unroll") for (int i=0;i<4;++i)                              \
          acc[i][j] = __builtin_amdgcn_mfma_f32_16x16x32_bf16(               \
              aR[i], bR, acc[i][j], 0,0,0);                                  \
        __builtin_amdgcn_s_setprio(0);                                       \
      }                                                                      \
    }                                                                        \
    BAR();                                                                   \
  }

  // prologue: tile 0 fully staged + drained
  STAGE(0,0,0); STAGE(0,1,0); STAGE(0,2,0); STAGE(0,3,0);
  GATE(0); BAR();

  for (int t=0; t<NT; t+=2){
    TILE_BODY(0, t)
    TILE_BODY(1, t+1)
  }
#undef TILE_BODY

  GATE(0);   // drain tail dummy DMAs before epilogue/retire

  // epilogue: acc[i][j]; frag row=(lane>>4)*4+r, col=lane&15
  #pragma unroll
  for (int i=0;i<4;++i){
    int rbase = rg0 + wrow + i*16 + ((lane>>4)<<2);
    #pragma unroll
    for (int j=0;j<4;++j){
      int cg = cg0 + wcol + j*16 + l15;
      float bn = (MODE!=2) ? bias[cg] : 0.f;
      #pragma unroll
      for (int r=0;r<4;++r){
        int rg = rbase + r;
        float v = acc[i][j][r];
        if (MODE==1 || MODE==3){ v += bn; v = gelu_f(v); }
        else if (MODE==2){ v += bias[rg]; v += ldr(resid[cbase + (size_t)rg*1024 + cg]); }
        else { v += bn; v += ldr(resid[cbase + (size_t)rg*1024 + cg]); }
        stv(&C[cbase + (size_t)rg*1024 + cg], v);
      }
    }
  }
}

extern "C" void kernel_launch(void* const* d_in, const int* in_sizes, int n_in,
                              void* d_out, int out_size, void* d_ws, size_t ws_size,
                              hipStream_t stream){
  const float* x    = (const float*)d_in[0];
  const float* tw1  = (const float*)d_in[1];
  const float* tb1  = (const float*)d_in[2];
  const float* tw2  = (const float*)d_in[3];
  const float* tb2  = (const float*)d_in[4];
  const float* cw1  = (const float*)d_in[5];
  const float* cb1  = (const float*)d_in[6];
  const float* cw2  = (const float*)d_in[7];
  const float* cb2  = (const float*)d_in[8];
  const float* g1   = (const float*)d_in[9];
  const float* bb1  = (const float*)d_in[10];
  const float* g2   = (const float*)d_in[11];
  const float* bb2  = (const float*)d_in[12];
  float* out = (float*)d_out;

  char* ws = (char*)d_ws;
  unsigned short* bufA = (unsigned short*)(ws);                    // 64MB bf16
  unsigned short* bufB = (unsigned short*)(ws + 67108864);         // 64MB bf16
  unsigned short* xmid = (unsigned short*)(ws + 134217728);        // 64MB bf16 x_mid
  unsigned short* w1m  = (unsigned short*)(ws + 201326592);        // 2MB
  unsigned short* w2m  = (unsigned short*)(ws + 203423744);        // 2MB
  unsigned short* c1b  = (unsigned short*)(ws + 205520896);        // 2MB
  unsigned short* c2b  = (unsigned short*)(ws + 207618048);        // 2MB
  float* meanb = (float*)(ws + 209715200);                         // 128KB
  float* rstdb = (float*)(ws + 209846272);                         // 128KB

  prep_weights<<<1024,256,0,stream>>>(tw1,tw2,cw1,cw2,w1m,w2m,c1b,c2b);
  // temporal path
  ln_stats<<<8192,256,0,stream>>>(x, meanb, rstdb);
  ln_norm_transpose<<<dim3(16,16,32),256,0,stream>>>(x, meanb, rstdb, g1, bb1, bufA);
  gemmw<1,unsigned short,float><<<512,1024,131072,stream>>>(bufA, w1m, bufB, tb1, (const float*)nullptr);
  gemmw<2,unsigned short,float><<<512,1024,131072,stream>>>(bufB, w2m, xmid, tb2, x);
  // channel path
  ln_fused<<<8192,256,0,stream>>>(xmid, g2, bb2, bufA);
  gemmw<3,unsigned short,unsigned short><<<512,1024,131072,stream>>>(bufA, c1b, bufB, cb1, (const unsigned short*)nullptr);
  gemmw<4,float,unsigned short><<<512,1024,131072,stream>>>(bufB, c2b, out, cb2, xmid);
}

// Round 18
// 450.129 us; speedup vs baseline: 1.1140x; 1.0743x over previous
//
#include <hip/hip_runtime.h>
#include <hip/hip_bf16.h>

#define BDIM 32
#define TDIM 1024
#define HDIM 1024
#define AS1 __attribute__((address_space(1)))
#define AS3 __attribute__((address_space(3)))

typedef __attribute__((ext_vector_type(8))) short short8;
typedef __attribute__((ext_vector_type(8))) unsigned short ushort8;
typedef __attribute__((ext_vector_type(4))) unsigned short u16x4;
typedef __attribute__((ext_vector_type(4))) float f32x4;

__device__ __forceinline__ float b2f(unsigned short h){ return __uint_as_float(((unsigned)h)<<16); }
__device__ __forceinline__ unsigned short f2b(float f){
  unsigned u = __float_as_uint(f);
  u += 0x7fffu + ((u>>16)&1u);
  return (unsigned short)(u>>16);
}
__device__ __forceinline__ float gelu_f(float v){ return 0.5f*v*(1.0f+erff(v*0.70710678118f)); }
__device__ __forceinline__ void stv(float* p, float v){ *p = v; }
__device__ __forceinline__ void stv(unsigned short* p, float v){ *p = f2b(v); }
__device__ __forceinline__ float ldr(float v){ return v; }
__device__ __forceinline__ float ldr(unsigned short v){ return b2f(v); }

// ---- convert weights fp32->bf16; tril-mask (incl. diagonal) the temporal ones ----
__global__ void prep_weights(const float* __restrict__ w1, const float* __restrict__ w2,
                             const float* __restrict__ c1, const float* __restrict__ c2,
                             unsigned short* __restrict__ w1m, unsigned short* __restrict__ w2m,
                             unsigned short* __restrict__ c1b, unsigned short* __restrict__ c2b){
  int idx = blockIdx.x*blockDim.x + threadIdx.x;
  int e = idx*4;
  int i = e >> 10, j0 = e & 1023;
  f32x4 a = *(const f32x4*)(w1+e);
  f32x4 b = *(const f32x4*)(w2+e);
  f32x4 c = *(const f32x4*)(c1+e);
  f32x4 d = *(const f32x4*)(c2+e);
  u16x4 av, bv, cv, dv;
  #pragma unroll
  for (int q=0;q<4;++q){
    float am = (j0+q <= i) ? a[q] : 0.f;
    float bm = (j0+q <= i) ? b[q] : 0.f;
    av[q]=f2b(am); bv[q]=f2b(bm); cv[q]=f2b(c[q]); dv[q]=f2b(d[q]);
  }
  *(u16x4*)(w1m+e)=av; *(u16x4*)(w2m+e)=bv; *(u16x4*)(c1b+e)=cv; *(u16x4*)(c2b+e)=dv;
}

// ---------------- LayerNorm row stats: one wave per 1024-wide fp32 row ----------------
__global__ void ln_stats(const float* __restrict__ p, float* __restrict__ mean,
                         float* __restrict__ rstd){
  int wid = threadIdx.x>>6, lane = threadIdx.x&63;
  int row = blockIdx.x*4 + wid;
  const float* pr = p + (size_t)row*HDIM;
  float s=0.f, s2=0.f;
  #pragma unroll
  for (int it=0; it<4; ++it){
    f32x4 v = *(const f32x4*)(pr + it*256 + lane*4);
    #pragma unroll
    for (int c=0;c<4;++c){ s += v[c]; s2 += v[c]*v[c]; }
  }
  #pragma unroll
  for (int off=32; off>0; off>>=1){ s += __shfl_xor(s,off,64); s2 += __shfl_xor(s2,off,64); }
  if (lane==0){
    float m = s * (1.0f/HDIM);
    float var = s2 * (1.0f/HDIM) - m*m;
    mean[row]=m; rstd[row]=rsqrtf(var + 1e-5f);
  }
}

// ---- normalize + transpose: x[b,t,h] fp32 -> xnT[b,h,t] bf16 (64x64 LDS tiles) ----
__global__ void ln_norm_transpose(const float* __restrict__ x, const float* __restrict__ mean,
                                  const float* __restrict__ rstd, const float* __restrict__ g,
                                  const float* __restrict__ bta, unsigned short* __restrict__ xnT){
  __shared__ float tile[64][65];
  int t0 = blockIdx.x*64, h0 = blockIdx.y*64, b = blockIdx.z;
  int tid = threadIdx.x;
  int rr = tid>>3, c8 = tid&7;
  size_t base = (size_t)b*TDIM*HDIM;
  #pragma unroll
  for (int p=0;p<2;++p){
    int r = rr + p*32;
    int trow = t0 + r;
    float m = mean[b*TDIM + trow], rs = rstd[b*TDIM + trow];
    f32x4 v0 = *(const f32x4*)(x + base + (size_t)trow*HDIM + h0 + c8*8);
    f32x4 v1 = *(const f32x4*)(x + base + (size_t)trow*HDIM + h0 + c8*8 + 4);
    #pragma unroll
    for (int c=0;c<4;++c){
      int h = c8*8+c;
      tile[r][h]   = (v0[c]-m)*rs*g[h0+h]   + bta[h0+h];
      tile[r][h+4] = (v1[c]-m)*rs*g[h0+h+4] + bta[h0+h+4];
    }
  }
  __syncthreads();
  #pragma unroll
  for (int p=0;p<2;++p){
    int hr = rr + p*32;
    ushort8 ov;
    #pragma unroll
    for (int c=0;c<8;++c) ov[c] = f2b(tile[c8*8+c][hr]);
    *(ushort8*)(xnT + base + (size_t)(h0+hr)*TDIM + t0 + c8*8) = ov;
  }
}

// ---- LN2 fused single-pass: bf16 in, bf16 out ----
__global__ void ln_fused(const unsigned short* __restrict__ p, const float* __restrict__ g,
                         const float* __restrict__ bta, unsigned short* __restrict__ o){
  int wid = threadIdx.x>>6, lane = threadIdx.x&63;
  size_t row = (size_t)blockIdx.x*4 + wid;
  const unsigned short* pr = p + row*HDIM + lane*16;
  ushort8 v0 = *(const ushort8*)(pr);
  ushort8 v1 = *(const ushort8*)(pr+8);
  float f[16];
  float s=0.f, s2=0.f;
  #pragma unroll
  for (int c=0;c<8;++c){ f[c]=b2f(v0[c]); f[c+8]=b2f(v1[c]); }
  #pragma unroll
  for (int c=0;c<16;++c){ s += f[c]; s2 += f[c]*f[c]; }
  #pragma unroll
  for (int off=32; off>0; off>>=1){ s += __shfl_xor(s,off,64); s2 += __shfl_xor(s2,off,64); }
  float m = s * (1.0f/HDIM);
  float rs = rsqrtf(s2*(1.0f/HDIM) - m*m + 1e-5f);
  int h0 = lane*16;
  ushort8 o0, o1;
  #pragma unroll
  for (int c=0;c<8;++c){
    o0[c] = f2b((f[c]-m)*rs*g[h0+c] + bta[h0+c]);
    o1[c] = f2b((f[c+8]-m)*rs*g[h0+c+8] + bta[h0+c+8]);
  }
  *(ushort8*)(o + row*HDIM + h0) = o0;
  *(ushort8*)(o + row*HDIM + h0 + 8) = o1;
}

// ======== 256x256 BK=64, 8-wave, quadrant-phase pipelined GEMM — barrier-diet (r13) ========
// Temporal modes (1/2): LPT dispatch — inner = 3-(bid>>7) so 16-K-tile blocks launch first;
// CUs that free early pick up progressively shorter blocks (makespan ~20 K-tiles/CU vs ~32
// with the old broken pairing). XCD-chunked panels within each class keep L2 locality.
#define GATE(N) asm volatile("s_waitcnt vmcnt(" #N ")" ::: "memory")
#define BAR()   __builtin_amdgcn_s_barrier()

template<int MODE, typename CT, typename RT>
__global__ __launch_bounds__(512,1)
void gemmq(const unsigned short* __restrict__ act, const unsigned short* __restrict__ wgt,
           CT* __restrict__ C, const float* __restrict__ bias, const RT* __restrict__ resid){
  extern __shared__ char LDS[];
  const int bid = blockIdx.x;
  int panel, inner;
  if constexpr (MODE==1 || MODE==2){
    inner = 3 - (bid >> 7);              // LPT: longest blocks dispatch first
    int lb = bid & 127;
    panel = (lb & 7)*16 + (lb >> 3);     // XCD-chunked within class
  } else {
    int tile = (bid & 7)*64 + (bid >> 3);
    panel = tile >> 2;
    inner = tile & 3;
  }
  const unsigned short *pa, *pb;
  size_t cbase; int rg0, cg0, kend;
  if constexpr (MODE==1){
    int b = panel>>2, mt = panel&3;
    pa = act + (size_t)b*1048576 + (size_t)mt*262144;
    pb = wgt + (size_t)inner*262144;
    kend = (inner+1)*256;
    cbase = (size_t)b*1048576; rg0 = mt*256; cg0 = inner*256;
  } else if constexpr (MODE==2){
    int b = panel>>2, nt = panel&3;
    pa = wgt + (size_t)inner*262144;
    pb = act + (size_t)b*1048576 + (size_t)nt*262144;
    kend = (inner+1)*256;
    cbase = (size_t)b*1048576; rg0 = inner*256; cg0 = nt*256;
  } else {
    pa = act + (size_t)panel*262144;
    pb = wgt + (size_t)inner*262144;
    kend = 1024;
    cbase = 0; rg0 = panel*256; cg0 = inner*256;
  }
  const int tid = threadIdx.x, lane = tid&63, wid = tid>>6;
  const int wrow = (wid>>2)*64;       // A-row base within quadrant
  const int wcol = (wid&3)*32;        // B-row (C-col) base within quadrant
  const int l15 = lane&15, l4b = (lane>>4)<<4;
  f32x4 acc[8][4];
  #pragma unroll
  for (int i=0;i<8;++i)
    #pragma unroll
    for (int j=0;j<4;++j) acc[i][j] = (f32x4)(0.f);

  const int NT = kend>>6;

  // half ids: 0=A rows0-127, 1=A rows128-255, 2=B rows0-127, 3=B rows128-255
  auto STAGE = [&](int dt, int half, int st){
    const unsigned short* src = (half<2) ? pa : pb;
    const int rbase = (half&1)<<7;
    char* dst = LDS + ((dt&1)<<16) + (half<<14);
    const int k0 = st<<6;
    #pragma unroll
    for (int l=0;l<2;++l){
      int W = tid*16 + (l<<13);
      int r = W>>7;
      int cs = (W&127) ^ ((r&7)<<4);            // inverse swizzle on global source
      __builtin_amdgcn_global_load_lds(
        (const AS1 void*)(src + (size_t)(rbase+r)*1024 + k0 + (cs>>1)),
        (AS3 void*)(dst + W), 16, 0, 0);
    }
  };
  auto STG = [&](int tt, int half, int t_now){ STAGE(tt, half, tt<NT ? tt : t_now); };

  auto LDA = [&](int buf, int qa, int i, int s)->short8{
    int ra = wrow + i*16 + l15;
    int L = (ra<<7) + (((s<<6) + l4b) ^ ((ra&7)<<4));
    return *(const short8*)(LDS + (buf<<16) + (qa<<14) + L);
  };
  auto LDB = [&](int buf, int qb, int j, int s)->short8{
    int rb = wcol + j*16 + l15;
    int L = (rb<<7) + (((s<<6) + l4b) ^ ((rb&7)<<4));
    return *(const short8*)(LDS + (buf<<16) + ((2+qb)<<14) + L);
  };

  short8 aR[2][4], bR[2][2];

#define MFMAQ(qa,qb)                                                         \
  __builtin_amdgcn_s_setprio(1);                                             \
  _Pragma("unroll") for (int s=0;s<2;++s)                                    \
    _Pragma("unroll") for (int i=0;i<4;++i)                                  \
      _Pragma("unroll") for (int j=0;j<2;++j)                                \
        acc[(qa)*4+i][(qb)*2+j] = __builtin_amdgcn_mfma_f32_16x16x32_bf16(   \
            aR[s][i], bR[s][j], acc[(qa)*4+i][(qb)*2+j], 0,0,0);             \
  __builtin_amdgcn_s_setprio(0);

  // prologue stream: A0(0), B0(0), A1(0), B1(0), A0(1)  -> gate: first 2 landed
  STAGE(0,0,0); STAGE(0,2,0); STAGE(0,1,0); STAGE(0,3,0);
  STAGE(1,0, 1<NT ? 1 : 0);
  GATE(6); BAR();

  for (int t=0; t<NT; ++t){
    const int buf = t&1;
    // ---- P0: reads A0+B0(t); stage B0(t+1); publish-gate; MFMA(0,0)
    #pragma unroll
    for (int s=0;s<2;++s){
      #pragma unroll
      for (int i=0;i<4;++i) aR[s][i] = LDA(buf,0,i,s);
      #pragma unroll
      for (int j=0;j<2;++j) bR[s][j] = LDB(buf,0,j,s);
    }
    STG(t+1, 2, t);
    GATE(4); BAR();
    MFMAQ(0,0)
    // ---- P1: read B1(t); stage A1(t+1); MFMA(0,1); BAR (A0-WAR fence)
    #pragma unroll
    for (int s=0;s<2;++s)
      #pragma unroll
      for (int j=0;j<2;++j) bR[s][j] = LDB(buf,1,j,s);
    STG(t+1, 1, t);
    MFMAQ(0,1)
    BAR();
    // ---- P2: read A1(t); stage B1(t+1); MFMA(1,1)
    #pragma unroll
    for (int s=0;s<2;++s)
      #pragma unroll
      for (int i=0;i<4;++i) aR[s][i] = LDA(buf,1,i,s);
    STG(t+1, 3, t);
    MFMAQ(1,1)
    // ---- P3: read B0(t); stage A0(t+2); MFMA(1,0); BAR (tile boundary fence)
    #pragma unroll
    for (int s=0;s<2;++s)
      #pragma unroll
      for (int j=0;j<2;++j) bR[s][j] = LDB(buf,0,j,s);
    STG(t+2, 0, t);
    MFMAQ(1,0)
    BAR();
  }
#undef MFMAQ

  // epilogue: acc[I][J], I=qa*4+i, J=qb*2+j; frag row=(lane>>4)*4+r, col=lane&15
  #pragma unroll
  for (int I=0;I<8;++I){
    int rbase = rg0 + (I>>2)*128 + wrow + (I&3)*16 + ((lane>>4)<<2);
    #pragma unroll
    for (int J=0;J<4;++J){
      int cg = cg0 + (J>>1)*128 + wcol + (J&1)*16 + l15;
      float bn = (MODE!=2) ? bias[cg] : 0.f;
      #pragma unroll
      for (int r=0;r<4;++r){
        int rg = rbase + r;
        float v = acc[I][J][r];
        if (MODE==1 || MODE==3){ v += bn; v = gelu_f(v); }
        else if (MODE==2){ v += bias[rg]; v += ldr(resid[cbase + (size_t)rg*1024 + cg]); }
        else { v += bn; v += ldr(resid[cbase + (size_t)rg*1024 + cg]); }
        stv(&C[cbase + (size_t)rg*1024 + cg], v);
      }
    }
  }
}

extern "C" void kernel_launch(void* const* d_in, const int* in_sizes, int n_in,
                              void* d_out, int out_size, void* d_ws, size_t ws_size,
                              hipStream_t stream){
  const float* x    = (const float*)d_in[0];
  const float* tw1  = (const float*)d_in[1];
  const float* tb1  = (const float*)d_in[2];
  const float* tw2  = (const float*)d_in[3];
  const float* tb2  = (const float*)d_in[4];
  const float* cw1  = (const float*)d_in[5];
  const float* cb1  = (const float*)d_in[6];
  const float* cw2  = (const float*)d_in[7];
  const float* cb2  = (const float*)d_in[8];
  const float* g1   = (const float*)d_in[9];
  const float* bb1  = (const float*)d_in[10];
  const float* g2   = (const float*)d_in[11];
  const float* bb2  = (const float*)d_in[12];
  float* out = (float*)d_out;

  char* ws = (char*)d_ws;
  unsigned short* bufA = (unsigned short*)(ws);                    // 64MB bf16
  unsigned short* bufB = (unsigned short*)(ws + 67108864);         // 64MB bf16
  unsigned short* xmid = (unsigned short*)(ws + 134217728);        // 64MB bf16 x_mid
  unsigned short* w1m  = (unsigned short*)(ws + 201326592);        // 2MB
  unsigned short* w2m  = (unsigned short*)(ws + 203423744);        // 2MB
  unsigned short* c1b  = (unsigned short*)(ws + 205520896);        // 2MB
  unsigned short* c2b  = (unsigned short*)(ws + 207618048);        // 2MB
  float* meanb = (float*)(ws + 209715200);                         // 128KB
  float* rstdb = (float*)(ws + 209846272);                         // 128KB

  prep_weights<<<1024,256,0,stream>>>(tw1,tw2,cw1,cw2,w1m,w2m,c1b,c2b);
  // temporal path
  ln_stats<<<8192,256,0,stream>>>(x, meanb, rstdb);
  ln_norm_transpose<<<dim3(16,16,32),256,0,stream>>>(x, meanb, rstdb, g1, bb1, bufA);
  gemmq<1,unsigned short,float><<<512,512,131072,stream>>>(bufA, w1m, bufB, tb1, (const float*)nullptr);
  gemmq<2,unsigned short,float><<<512,512,131072,stream>>>(bufB, w2m, xmid, tb2, x);
  // channel path
  ln_fused<<<8192,256,0,stream>>>(xmid, g2, bb2, bufA);
  gemmq<3,unsigned short,unsigned short><<<512,512,131072,stream>>>(bufA, c1b, bufB, cb1, (const unsigned short*)nullptr);
  gemmq<4,float,unsigned short><<<512,512,131072,stream>>>(bufB, c2b, out, cb2, xmid);
}